// Round 4
// baseline (982.749 us; speedup 1.0000x reference)
//
#include <hip/hip_runtime.h>
#include <hip/hip_bf16.h>

#define HID 64
#define NGRAPHS 64
#define BUCKET 64        // nodes per bucket (dst >> 6)
#define ECHUNK 1024      // entries staged to LDS per pass in bucket_aggv
#define EPB 8192         // edges per block in bin_count / bin_scatter

// ---------------------------------------------------------------------------
// Detect whether edge_index / batch are int64 or int32 on device.
// Samples int64 reads within the first half of each buffer (in-bounds for
// either dtype). int32 data read as int64 pairs random indices -> virtually
// never all in [0, range). flags[0]=edge is 64-bit, flags[1]=batch is 64-bit.
// ---------------------------------------------------------------------------
__global__ __launch_bounds__(64) void detect_kernel(const void* edge, const void* batch,
                                                    int* flags, int E2, int N, int G) {
    int lane = threadIdx.x;
    int half = E2 / 2;
    int stride = half / 64; if (stride < 1) stride = 1;
    int j = lane * stride; if (j >= half) j = half - 1;
    long long v = ((const long long*)edge)[j];
    bool ok = (v >= 0 && v < (long long)N);
    unsigned long long m = __ballot(ok);
    if (lane == 0) flags[0] = (m == ~0ULL) ? 1 : 0;
    int halfB = N / 2;
    int strideB = halfB / 64; if (strideB < 1) strideB = 1;
    int jb = lane * strideB; if (jb >= halfB) jb = halfB - 1;
    long long vb = ((const long long*)batch)[jb];
    bool okb = (vb >= 0 && vb < (long long)G);
    unsigned long long mb = __ballot(okb);
    if (lane == 0) flags[1] = (mb == ~0ULL) ? 1 : 0;
}

__device__ __forceinline__ int idx_at(const void* p, int i, bool is64) {
    return is64 ? (int)((const long long*)p)[i] : ((const int*)p)[i];
}

// ---------------------------------------------------------------------------
// Bucket histogram: LDS-local counts, one global add per (block, bucket).
// ---------------------------------------------------------------------------
__global__ __launch_bounds__(256) void bin_count_kernel(const void* edge, const int* __restrict__ flags,
                                                        int* __restrict__ bcnt, int E, int NB) {
    extern __shared__ int hist[];   // NB ints
    for (int i = threadIdx.x; i < NB; i += 256) hist[i] = 0;
    __syncthreads();
    bool is64 = flags[0] != 0;
    int start = blockIdx.x * EPB;
    int end = start + EPB; if (end > E) end = E;
    for (int e = start + threadIdx.x; e < end; e += 256) {
        int d = idx_at(edge, E + e, is64);
        atomicAdd(&hist[d >> 6], 1);
    }
    __syncthreads();
    for (int i = threadIdx.x; i < NB; i += 256) {
        int h = hist[i];
        if (h) atomicAdd(&bcnt[i], h);
    }
}

// ---------------------------------------------------------------------------
// Exclusive scan of bucket counts (NB <= 1024): bbase[NB+1], bcursor init.
// ---------------------------------------------------------------------------
__global__ __launch_bounds__(1024) void bin_scan_kernel(const int* __restrict__ bcnt,
                                                        int* __restrict__ bbase,
                                                        int* __restrict__ bcursor, int NB) {
    __shared__ int s[1024];
    int t = threadIdx.x;
    int v = (t < NB) ? bcnt[t] : 0;
    s[t] = v;
    __syncthreads();
    for (int off = 1; off < 1024; off <<= 1) {
        int tmp = (t >= off) ? s[t - off] : 0;
        __syncthreads();
        s[t] += tmp;
        __syncthreads();
    }
    if (t < NB) {
        int ex = s[t] - v;
        bbase[t] = ex;
        bcursor[t] = ex;
        if (t == NB - 1) bbase[NB] = s[t];
    }
}

// ---------------------------------------------------------------------------
// Bucket scatter: per-block histogram -> one range reservation per bucket ->
// contiguous packed-entry appends. entry = (src << 6) | (dst & 63).
// ---------------------------------------------------------------------------
__global__ __launch_bounds__(256) void bin_scatter_kernel(const void* edge, const int* __restrict__ flags,
                                                          int* __restrict__ bcursor,
                                                          unsigned int* __restrict__ entries,
                                                          int E, int NB) {
    extern __shared__ int lds[];    // hist[NB] + base[NB]
    int* hist = lds;
    int* base = lds + NB;
    for (int i = threadIdx.x; i < NB; i += 256) hist[i] = 0;
    __syncthreads();
    bool is64 = flags[0] != 0;
    int start = blockIdx.x * EPB;
    int end = start + EPB; if (end > E) end = E;
    for (int e = start + threadIdx.x; e < end; e += 256) {
        int d = idx_at(edge, E + e, is64);
        atomicAdd(&hist[d >> 6], 1);
    }
    __syncthreads();
    for (int i = threadIdx.x; i < NB; i += 256) {
        int h = hist[i];
        base[i] = h ? atomicAdd(&bcursor[i], h) : 0;
    }
    __syncthreads();
    for (int i = threadIdx.x; i < NB; i += 256) hist[i] = 0;  // reuse as local cursor
    __syncthreads();
    for (int e = start + threadIdx.x; e < end; e += 256) {
        int srcv = idx_at(edge, e, is64);
        int d = idx_at(edge, E + e, is64);
        int b = d >> 6;
        int lo = atomicAdd(&hist[b], 1);
        entries[base[b] + lo] = ((unsigned int)srcv << 6) | (unsigned int)(d & 63);
    }
}

// ---------------------------------------------------------------------------
// Layer 1 bucket aggregation (scalar feature) + degree extraction.
// One block per bucket; LDS accumulate; writes mean1[] and invdeg[].
// ---------------------------------------------------------------------------
__global__ __launch_bounds__(256) void bucket_agg1_kernel(const unsigned int* __restrict__ entries,
                                                          const int* __restrict__ bbase,
                                                          const float* __restrict__ x,
                                                          float* __restrict__ mean1,
                                                          float* __restrict__ invdeg, int N) {
    __shared__ float acc[BUCKET];
    __shared__ int cnt[BUCKET];
    int t = threadIdx.x;
    int b = blockIdx.x;
    if (t < BUCKET) { acc[t] = 0.0f; cnt[t] = 0; }
    __syncthreads();
    int r0 = bbase[b], r1 = bbase[b + 1];
    for (int j = r0 + t; j < r1; j += 256) {
        unsigned int en = entries[j];
        int srcv = (int)(en >> 6), dl = (int)(en & 63u);
        atomicAdd(&acc[dl], x[srcv]);
        atomicAdd(&cnt[dl], 1);
    }
    __syncthreads();
    int node = b * BUCKET + t;
    if (t < BUCKET && node < N) {
        float inv = 1.0f / fmaxf((float)cnt[t], 1.0f);
        mean1[node] = acc[t] * inv;          // isolated node: acc=0 -> 0
        invdeg[node] = inv;
    }
}

// Layer 1 node transform: h1[i][f] = relu(mean1_i*W1l[f] + b1[f] + x_i*W1r[f]) + x_i
__global__ __launch_bounds__(256) void node1_kernel(const float* __restrict__ x,
                                                    const float* __restrict__ mean1,
                                                    const float* __restrict__ W1l,
                                                    const float* __restrict__ b1,
                                                    const float* __restrict__ W1r,
                                                    float* __restrict__ h1, int N) {
    int tid = blockIdx.x * blockDim.x + threadIdx.x;
    if (tid >= N * HID) return;
    int i = tid >> 6, f = tid & 63;
    float xv = x[i];
    float v = mean1[i] * W1l[f] + b1[f] + xv * W1r[f];
    v = v > 0.0f ? v : 0.0f;
    h1[tid] = v + xv;
}

// ---------------------------------------------------------------------------
// Layers 2/3 bucket aggregation: one block per bucket, acc[64][64] in LDS.
// Wave reads one h-row per entry (lane = feature, coalesced 256 B), ds_add
// into acc (2-way bank aliasing = free). Entries staged to LDS in chunks.
// Writes mean rows coalesced, scaled by invdeg.
// ---------------------------------------------------------------------------
__global__ __launch_bounds__(256) void bucket_aggv_kernel(const unsigned int* __restrict__ entries,
                                                          const int* __restrict__ bbase,
                                                          const float* __restrict__ h,
                                                          const float* __restrict__ invdeg,
                                                          float* __restrict__ mean, int N) {
    __shared__ float acc[BUCKET][HID];      // 16 KB
    __shared__ unsigned int se[ECHUNK];     // 4 KB
    int t = threadIdx.x;
    int b = blockIdx.x;
    for (int i = t; i < BUCKET * HID; i += 256) ((float*)acc)[i] = 0.0f;
    int r0 = bbase[b], r1 = bbase[b + 1];
    int wave = t >> 6, lane = t & 63;
    for (int cbase = r0; cbase < r1; cbase += ECHUNK) {
        int m = r1 - cbase; if (m > ECHUNK) m = ECHUNK;
        __syncthreads();
        for (int i = t; i < m; i += 256) se[i] = entries[cbase + i];
        __syncthreads();
        for (int i = wave; i < m; i += 4) {
            unsigned int en = se[i];
            int srcv = (int)(en >> 6), dl = (int)(en & 63u);
            float v = h[(size_t)srcv * HID + lane];
            atomicAdd(&acc[dl][lane], v);
        }
    }
    __syncthreads();
    int nodebase = b * BUCKET;
    for (int i = t; i < BUCKET * HID; i += 256) {
        int dl = i >> 6, f = i & 63;
        int node = nodebase + dl;
        if (node < N) mean[(size_t)node * HID + f] = acc[dl][f] * invdeg[node];
    }
}

// ---------------------------------------------------------------------------
// Layers 2/3 node transform. Weights staged in LDS; 4 nodes per block pass.
// hout[i][f] = relu( sum_k mean[i][k]*Wl[k][f] + hprev[i][k]*Wr[k][f] + b[f] ) + hprev[i][f]
// ---------------------------------------------------------------------------
__global__ __launch_bounds__(256) void node_layer_kernel(const float* __restrict__ hprev,
                                                         const float* __restrict__ mean,
                                                         const float* __restrict__ Wl,
                                                         const float* __restrict__ bvec,
                                                         const float* __restrict__ Wr,
                                                         float* __restrict__ hout, int N) {
    __shared__ float sWl[HID * HID];
    __shared__ float sWr[HID * HID];
    __shared__ float sMean[4][HID];
    __shared__ float sHp[4][HID];
    for (int idx = threadIdx.x; idx < HID * HID; idx += 256) {
        sWl[idx] = Wl[idx];
        sWr[idx] = Wr[idx];
    }
    __syncthreads();
    int f = threadIdx.x & 63;
    int sub = threadIdx.x >> 6;  // 0..3
    float bf = bvec[f];
    int ngroups = (N + 3) >> 2;
    for (int grp = blockIdx.x; grp < ngroups; grp += gridDim.x) {
        int i = grp * 4 + sub;
        if (i < N) {
            sMean[sub][f] = mean[(size_t)i * HID + f];
            sHp[sub][f] = hprev[(size_t)i * HID + f];
        }
        __syncthreads();
        if (i < N) {
            float acc = bf;
#pragma unroll
            for (int k = 0; k < HID; ++k) {
                acc += sMean[sub][k] * sWl[k * HID + f] + sHp[sub][k] * sWr[k * HID + f];
            }
            float r = acc > 0.0f ? acc : 0.0f;
            hout[(size_t)i * HID + f] = r + sHp[sub][f];
        }
        __syncthreads();
    }
}

// ---------------------------------------------------------------------------
// Global mean pool: batch is sorted -> run-length accumulate per wave.
// ---------------------------------------------------------------------------
__global__ __launch_bounds__(256) void pool_kernel(const float* __restrict__ h,
                                                   const void* batch,
                                                   const int* __restrict__ flags,
                                                   float* __restrict__ psum,
                                                   int* __restrict__ gcnt,
                                                   int N, int nodesPerWave) {
    int wave = (blockIdx.x * blockDim.x + threadIdx.x) >> 6;
    int f = threadIdx.x & 63;
    int start = wave * nodesPerWave;
    if (start >= N) return;
    bool is64 = flags[1] != 0;
    int end = start + nodesPerWave;
    if (end > N) end = N;
    int g = idx_at(batch, start, is64);
    float acc = 0.0f;
    int c = 0;
    for (int i = start; i < end; ++i) {
        int gi = idx_at(batch, i, is64);
        if (gi != g) {
            atomicAdd(&psum[g * HID + f], acc);
            if (f == 0) atomicAdd(&gcnt[g], c);
            acc = 0.0f; c = 0; g = gi;
        }
        acc += h[(size_t)i * HID + f];
        c++;
    }
    atomicAdd(&psum[g * HID + f], acc);
    if (f == 0) atomicAdd(&gcnt[g], c);
}

// ---------------------------------------------------------------------------
// FC head: one block (64 threads) per graph.
// ---------------------------------------------------------------------------
__global__ __launch_bounds__(64) void fc_kernel(const float* __restrict__ psum,
                                                const int* __restrict__ gcnt,
                                                const float* __restrict__ Wfc1,
                                                const float* __restrict__ bfc1,
                                                const float* __restrict__ Wfc2,
                                                const float* __restrict__ bfc2,
                                                float* __restrict__ out) {
    int g = blockIdx.x;
    int t = threadIdx.x;
    __shared__ float mean[HID];
    float c = fmaxf((float)gcnt[g], 1.0f);
    mean[t] = psum[g * HID + t] / c;
    __syncthreads();
    float v = 0.0f;
    if (t < 32) {
        float acc = bfc1[t];
#pragma unroll
        for (int k = 0; k < HID; ++k) acc += mean[k] * Wfc1[k * 32 + t];
        float hcc = acc > 0.0f ? acc : 0.0f;
        v = hcc * Wfc2[t];
    }
#pragma unroll
    for (int off = 32; off >= 1; off >>= 1) v += __shfl_down(v, off);
    if (t == 0) out[g] = v + bfc2[0];
}

extern "C" void kernel_launch(void* const* d_in, const int* in_sizes, int n_in,
                              void* d_out, int out_size, void* d_ws, size_t ws_size,
                              hipStream_t stream) {
    const int N = in_sizes[0];       // 50000
    const int E2 = in_sizes[1];      // 2*E
    const int E = E2 / 2;
    const int NB = (N + BUCKET - 1) / BUCKET;   // 782

    const float* x    = (const float*)d_in[0];
    const void*  edge = d_in[1];
    const void*  batch= d_in[2];
    const float* W1l  = (const float*)d_in[3];
    const float* b1   = (const float*)d_in[4];
    const float* W1r  = (const float*)d_in[5];
    const float* W2l  = (const float*)d_in[6];
    const float* b2   = (const float*)d_in[7];
    const float* W2r  = (const float*)d_in[8];
    const float* W3l  = (const float*)d_in[9];
    const float* b3   = (const float*)d_in[10];
    const float* W3r  = (const float*)d_in[11];
    const float* Wfc1 = (const float*)d_in[12];
    const float* bfc1 = (const float*)d_in[13];
    const float* Wfc2 = (const float*)d_in[14];
    const float* bfc2 = (const float*)d_in[15];
    float* out = (float*)d_out;

    // Workspace layout (256 B aligned slices)
    char* ws = (char*)d_ws;
    size_t o = 0;
    auto alloc = [&](size_t bytes) { char* p = ws + o; o += (bytes + 255) & ~(size_t)255; return p; };
    int*   bcnt    = (int*)alloc((size_t)NB * 4);
    int*   bbase   = (int*)alloc(((size_t)NB + 1) * 4);
    int*   bcursor = (int*)alloc((size_t)NB * 4);
    unsigned int* entries = (unsigned int*)alloc((size_t)E * 4);
    float* invdeg  = (float*)alloc((size_t)N * 4);
    float* mean1   = (float*)alloc((size_t)N * 4);
    float* h1      = (float*)alloc((size_t)N * HID * 4);   // reused as h3
    float* meanb   = (float*)alloc((size_t)N * HID * 4);
    float* h2      = (float*)alloc((size_t)N * HID * 4);
    float* psum    = (float*)alloc((size_t)NGRAPHS * HID * 4);
    int*   gcnt    = (int*)alloc((size_t)NGRAPHS * 4);
    int*   flags   = (int*)alloc(16);
    float* h3 = h1;

    // Zero what must be zero (ws is poisoned 0xAA before every call)
    hipMemsetAsync(bcnt, 0, (size_t)NB * 4, stream);
    hipMemsetAsync(psum, 0, (size_t)NGRAPHS * HID * 4 + 256, stream);  // psum + gcnt (adjacent slices)

    // Index dtype detection
    detect_kernel<<<1, 64, 0, stream>>>(edge, batch, flags, E2, N, NGRAPHS);

    // Bucket binning: count -> scan -> scatter
    const int nblk = (E + EPB - 1) / EPB;   // 98
    bin_count_kernel<<<nblk, 256, NB * 4, stream>>>(edge, flags, bcnt, E, NB);
    bin_scan_kernel<<<1, 1024, 0, stream>>>(bcnt, bbase, bcursor, NB);
    bin_scatter_kernel<<<nblk, 256, 2 * NB * 4, stream>>>(edge, flags, bcursor, entries, E, NB);

    // Layer 1
    bucket_agg1_kernel<<<NB, 256, 0, stream>>>(entries, bbase, x, mean1, invdeg, N);
    node1_kernel<<<((size_t)N * HID + 255) / 256, 256, 0, stream>>>(x, mean1, W1l, b1, W1r, h1, N);

    // Layer 2
    bucket_aggv_kernel<<<NB, 256, 0, stream>>>(entries, bbase, h1, invdeg, meanb, N);
    node_layer_kernel<<<1024, 256, 0, stream>>>(h1, meanb, W2l, b2, W2r, h2, N);

    // Layer 3
    bucket_aggv_kernel<<<NB, 256, 0, stream>>>(entries, bbase, h2, invdeg, meanb, N);
    node_layer_kernel<<<1024, 256, 0, stream>>>(h2, meanb, W3l, b3, W3r, h3, N);

    // Pool + FC head
    {
        int nodesPerWave = 64;
        int waves = (N + nodesPerWave - 1) / nodesPerWave;
        int threads = waves * 64;
        pool_kernel<<<(threads + 255) / 256, 256, 0, stream>>>(h3, batch, flags, psum, gcnt,
                                                               N, nodesPerWave);
    }
    fc_kernel<<<NGRAPHS, 64, 0, stream>>>(psum, gcnt, Wfc1, bfc1, Wfc2, bfc2, out);
}

// Round 5
// 343.414 us; speedup vs baseline: 2.8617x; 2.8617x over previous
//
#include <hip/hip_runtime.h>
#include <hip/hip_bf16.h>

#define HID 64
#define NGRAPHS 64
#define BUCKET 64        // nodes per bucket (dst >> 6)
#define EPB 4096         // edges per block in bin_count / bin_scatter

// ---------------------------------------------------------------------------
// Detect whether edge_index / batch are int64 or int32 on device.
// Samples int64 reads within the first half of each buffer (in-bounds for
// either dtype). int32 data read as int64 pairs random indices -> virtually
// never all in [0, range). flags[0]=edge is 64-bit, flags[1]=batch is 64-bit.
// ---------------------------------------------------------------------------
__global__ __launch_bounds__(64) void detect_kernel(const void* edge, const void* batch,
                                                    int* flags, int E2, int N, int G) {
    int lane = threadIdx.x;
    int half = E2 / 2;
    int stride = half / 64; if (stride < 1) stride = 1;
    int j = lane * stride; if (j >= half) j = half - 1;
    long long v = ((const long long*)edge)[j];
    bool ok = (v >= 0 && v < (long long)N);
    unsigned long long m = __ballot(ok);
    if (lane == 0) flags[0] = (m == ~0ULL) ? 1 : 0;
    int halfB = N / 2;
    int strideB = halfB / 64; if (strideB < 1) strideB = 1;
    int jb = lane * strideB; if (jb >= halfB) jb = halfB - 1;
    long long vb = ((const long long*)batch)[jb];
    bool okb = (vb >= 0 && vb < (long long)G);
    unsigned long long mb = __ballot(okb);
    if (lane == 0) flags[1] = (mb == ~0ULL) ? 1 : 0;
}

__device__ __forceinline__ int idx_at(const void* p, int i, bool is64) {
    return is64 ? (int)((const long long*)p)[i] : ((const int*)p)[i];
}

// ---------------------------------------------------------------------------
// Bucket histogram: LDS-local counts, one global add per (block, bucket).
// ---------------------------------------------------------------------------
__global__ __launch_bounds__(256) void bin_count_kernel(const void* edge, const int* __restrict__ flags,
                                                        int* __restrict__ bcnt, int E, int NB) {
    extern __shared__ int hist[];   // NB ints
    for (int i = threadIdx.x; i < NB; i += 256) hist[i] = 0;
    __syncthreads();
    bool is64 = flags[0] != 0;
    int start = blockIdx.x * EPB;
    int end = start + EPB; if (end > E) end = E;
    for (int e = start + threadIdx.x; e < end; e += 256) {
        int d = idx_at(edge, E + e, is64);
        atomicAdd(&hist[d >> 6], 1);
    }
    __syncthreads();
    for (int i = threadIdx.x; i < NB; i += 256) {
        int h = hist[i];
        if (h) atomicAdd(&bcnt[i], h);
    }
}

// ---------------------------------------------------------------------------
// Exclusive scan of bucket counts (NB <= 1024): bbase[NB+1], bcursor init.
// ---------------------------------------------------------------------------
__global__ __launch_bounds__(1024) void bin_scan_kernel(const int* __restrict__ bcnt,
                                                        int* __restrict__ bbase,
                                                        int* __restrict__ bcursor, int NB) {
    __shared__ int s[1024];
    int t = threadIdx.x;
    int v = (t < NB) ? bcnt[t] : 0;
    s[t] = v;
    __syncthreads();
    for (int off = 1; off < 1024; off <<= 1) {
        int tmp = (t >= off) ? s[t - off] : 0;
        __syncthreads();
        s[t] += tmp;
        __syncthreads();
    }
    if (t < NB) {
        int ex = s[t] - v;
        bbase[t] = ex;
        bcursor[t] = ex;
        if (t == NB - 1) bbase[NB] = s[t];
    }
}

// ---------------------------------------------------------------------------
// Bucket scatter: per-block histogram -> one range reservation per bucket ->
// contiguous packed-entry appends. entry = (src << 6) | (dst & 63).
// ---------------------------------------------------------------------------
__global__ __launch_bounds__(256) void bin_scatter_kernel(const void* edge, const int* __restrict__ flags,
                                                          int* __restrict__ bcursor,
                                                          unsigned int* __restrict__ entries,
                                                          int E, int NB) {
    extern __shared__ int lds[];    // hist[NB] + base[NB]
    int* hist = lds;
    int* base = lds + NB;
    for (int i = threadIdx.x; i < NB; i += 256) hist[i] = 0;
    __syncthreads();
    bool is64 = flags[0] != 0;
    int start = blockIdx.x * EPB;
    int end = start + EPB; if (end > E) end = E;
    for (int e = start + threadIdx.x; e < end; e += 256) {
        int d = idx_at(edge, E + e, is64);
        atomicAdd(&hist[d >> 6], 1);
    }
    __syncthreads();
    for (int i = threadIdx.x; i < NB; i += 256) {
        int h = hist[i];
        base[i] = h ? atomicAdd(&bcursor[i], h) : 0;
    }
    __syncthreads();
    for (int i = threadIdx.x; i < NB; i += 256) hist[i] = 0;  // reuse as local cursor
    __syncthreads();
    for (int e = start + threadIdx.x; e < end; e += 256) {
        int srcv = idx_at(edge, e, is64);
        int d = idx_at(edge, E + e, is64);
        int b = d >> 6;
        int lo = atomicAdd(&hist[b], 1);
        entries[base[b] + lo] = ((unsigned int)srcv << 6) | (unsigned int)(d & 63);
    }
}

// ---------------------------------------------------------------------------
// Per-bucket CSR finalize: one block per bucket. Histogram the bucket's 64
// destinations, wave-prefix-scan, write rowptr (coalesced) and scatter src
// into csr within the bucket's contiguous window (high cacheline reuse).
// ---------------------------------------------------------------------------
__global__ __launch_bounds__(256) void csr_finalize_kernel(const unsigned int* __restrict__ entries,
                                                           const int* __restrict__ bbase,
                                                           int* __restrict__ rowptr,
                                                           int* __restrict__ csr,
                                                           int N, int NB) {
    __shared__ int hist[BUCKET];
    __shared__ int lstart[BUCKET];
    __shared__ int lcur[BUCKET];
    int t = threadIdx.x;
    int b = blockIdx.x;
    if (t < BUCKET) { hist[t] = 0; lcur[t] = 0; }
    __syncthreads();
    int r0 = bbase[b], r1 = bbase[b + 1];
    for (int j = r0 + t; j < r1; j += 256) {
        atomicAdd(&hist[entries[j] & 63u], 1);
    }
    __syncthreads();
    if (t < BUCKET) {  // wave 0: 64-lane inclusive shuffle scan -> exclusive
        int v = hist[t];
        int s = v;
#pragma unroll
        for (int off = 1; off < 64; off <<= 1) {
            int u = __shfl_up(s, off);
            if (t >= off) s += u;
        }
        lstart[t] = s - v;
        int node = b * BUCKET + t;
        if (node < N) rowptr[node] = r0 + s - v;
        if (b == NB - 1 && t == 63) rowptr[N] = r1;
    }
    __syncthreads();
    for (int j = r0 + t; j < r1; j += 256) {
        unsigned int en = entries[j];
        int dl = (int)(en & 63u);
        int p = atomicAdd(&lcur[dl], 1);
        csr[r0 + lstart[dl] + p] = (int)(en >> 6);
    }
}

// ---------------------------------------------------------------------------
// Layer 1 aggregation (scalar feature): gather mean of x over neighbors.
// ---------------------------------------------------------------------------
__global__ __launch_bounds__(256) void gather1_kernel(const int* __restrict__ rowptr,
                                                      const int* __restrict__ csr,
                                                      const float* __restrict__ x,
                                                      float* __restrict__ mean1, int N) {
    int i = blockIdx.x * blockDim.x + threadIdx.x;
    if (i >= N) return;
    int r0 = rowptr[i], r1 = rowptr[i + 1];
    float s = 0.0f;
    for (int j = r0; j < r1; ++j) s += x[csr[j]];
    mean1[i] = (r1 > r0) ? s / (float)(r1 - r0) : 0.0f;
}

// Layer 1 node transform: h1[i][f] = relu(mean1_i*W1l[f] + b1[f] + x_i*W1r[f]) + x_i
__global__ __launch_bounds__(256) void node1_kernel(const float* __restrict__ x,
                                                    const float* __restrict__ mean1,
                                                    const float* __restrict__ W1l,
                                                    const float* __restrict__ b1,
                                                    const float* __restrict__ W1r,
                                                    float* __restrict__ h1, int N) {
    int tid = blockIdx.x * blockDim.x + threadIdx.x;
    if (tid >= N * HID) return;
    int i = tid >> 6, f = tid & 63;
    float xv = x[i];
    float v = mean1[i] * W1l[f] + b1[f] + xv * W1r[f];
    v = v > 0.0f ? v : 0.0f;
    h1[tid] = v + xv;
}

// ---------------------------------------------------------------------------
// Layers 2/3 aggregation via gather: 16 lanes per node, float4 per lane.
// Writes the MEAN row directly (degree = rowptr diff). No atomics.
// ---------------------------------------------------------------------------
__global__ __launch_bounds__(256) void gather_mean_kernel(const int* __restrict__ rowptr,
                                                          const int* __restrict__ csr,
                                                          const float* __restrict__ h,
                                                          float* __restrict__ mean, int N) {
    int grp = threadIdx.x >> 4;      // 16 groups per block
    int l = threadIdx.x & 15;        // lane within group -> one float4 of the row
    int i = blockIdx.x * 16 + grp;
    if (i >= N) return;
    int r0 = rowptr[i], r1 = rowptr[i + 1];
    float4 acc = make_float4(0.f, 0.f, 0.f, 0.f);
    for (int j = r0; j < r1; ++j) {
        int s = csr[j];
        const float4 v = *(const float4*)(h + (size_t)s * HID + l * 4);
        acc.x += v.x; acc.y += v.y; acc.z += v.z; acc.w += v.w;
    }
    float inv = (r1 > r0) ? 1.0f / (float)(r1 - r0) : 0.0f;
    acc.x *= inv; acc.y *= inv; acc.z *= inv; acc.w *= inv;
    *(float4*)(mean + (size_t)i * HID + l * 4) = acc;
}

// ---------------------------------------------------------------------------
// Layers 2/3 node transform. Weights staged in LDS; 4 nodes per block pass.
// hout[i][f] = relu( sum_k mean[i][k]*Wl[k][f] + hprev[i][k]*Wr[k][f] + b[f] ) + hprev[i][f]
// ---------------------------------------------------------------------------
__global__ __launch_bounds__(256) void node_layer_kernel(const float* __restrict__ hprev,
                                                         const float* __restrict__ mean,
                                                         const float* __restrict__ Wl,
                                                         const float* __restrict__ bvec,
                                                         const float* __restrict__ Wr,
                                                         float* __restrict__ hout, int N) {
    __shared__ float sWl[HID * HID];
    __shared__ float sWr[HID * HID];
    __shared__ float sMean[4][HID];
    __shared__ float sHp[4][HID];
    for (int idx = threadIdx.x; idx < HID * HID; idx += 256) {
        sWl[idx] = Wl[idx];
        sWr[idx] = Wr[idx];
    }
    __syncthreads();
    int f = threadIdx.x & 63;
    int sub = threadIdx.x >> 6;  // 0..3
    float bf = bvec[f];
    int ngroups = (N + 3) >> 2;
    for (int grp = blockIdx.x; grp < ngroups; grp += gridDim.x) {
        int i = grp * 4 + sub;
        if (i < N) {
            sMean[sub][f] = mean[(size_t)i * HID + f];
            sHp[sub][f] = hprev[(size_t)i * HID + f];
        }
        __syncthreads();
        if (i < N) {
            float acc = bf;
#pragma unroll
            for (int k = 0; k < HID; ++k) {
                acc += sMean[sub][k] * sWl[k * HID + f] + sHp[sub][k] * sWr[k * HID + f];
            }
            float r = acc > 0.0f ? acc : 0.0f;
            hout[(size_t)i * HID + f] = r + sHp[sub][f];
        }
        __syncthreads();
    }
}

// ---------------------------------------------------------------------------
// Global mean pool: batch is sorted -> run-length accumulate per wave.
// ---------------------------------------------------------------------------
__global__ __launch_bounds__(256) void pool_kernel(const float* __restrict__ h,
                                                   const void* batch,
                                                   const int* __restrict__ flags,
                                                   float* __restrict__ psum,
                                                   int* __restrict__ gcnt,
                                                   int N, int nodesPerWave) {
    int wave = (blockIdx.x * blockDim.x + threadIdx.x) >> 6;
    int f = threadIdx.x & 63;
    int start = wave * nodesPerWave;
    if (start >= N) return;
    bool is64 = flags[1] != 0;
    int end = start + nodesPerWave;
    if (end > N) end = N;
    int g = idx_at(batch, start, is64);
    float acc = 0.0f;
    int c = 0;
    for (int i = start; i < end; ++i) {
        int gi = idx_at(batch, i, is64);
        if (gi != g) {
            atomicAdd(&psum[g * HID + f], acc);
            if (f == 0) atomicAdd(&gcnt[g], c);
            acc = 0.0f; c = 0; g = gi;
        }
        acc += h[(size_t)i * HID + f];
        c++;
    }
    atomicAdd(&psum[g * HID + f], acc);
    if (f == 0) atomicAdd(&gcnt[g], c);
}

// ---------------------------------------------------------------------------
// FC head: one block (64 threads) per graph.
// ---------------------------------------------------------------------------
__global__ __launch_bounds__(64) void fc_kernel(const float* __restrict__ psum,
                                                const int* __restrict__ gcnt,
                                                const float* __restrict__ Wfc1,
                                                const float* __restrict__ bfc1,
                                                const float* __restrict__ Wfc2,
                                                const float* __restrict__ bfc2,
                                                float* __restrict__ out) {
    int g = blockIdx.x;
    int t = threadIdx.x;
    __shared__ float mean[HID];
    float c = fmaxf((float)gcnt[g], 1.0f);
    mean[t] = psum[g * HID + t] / c;
    __syncthreads();
    float v = 0.0f;
    if (t < 32) {
        float acc = bfc1[t];
#pragma unroll
        for (int k = 0; k < HID; ++k) acc += mean[k] * Wfc1[k * 32 + t];
        float hcc = acc > 0.0f ? acc : 0.0f;
        v = hcc * Wfc2[t];
    }
#pragma unroll
    for (int off = 32; off >= 1; off >>= 1) v += __shfl_down(v, off);
    if (t == 0) out[g] = v + bfc2[0];
}

extern "C" void kernel_launch(void* const* d_in, const int* in_sizes, int n_in,
                              void* d_out, int out_size, void* d_ws, size_t ws_size,
                              hipStream_t stream) {
    const int N = in_sizes[0];       // 50000
    const int E2 = in_sizes[1];      // 2*E
    const int E = E2 / 2;
    const int NB = (N + BUCKET - 1) / BUCKET;   // 782

    const float* x    = (const float*)d_in[0];
    const void*  edge = d_in[1];
    const void*  batch= d_in[2];
    const float* W1l  = (const float*)d_in[3];
    const float* b1   = (const float*)d_in[4];
    const float* W1r  = (const float*)d_in[5];
    const float* W2l  = (const float*)d_in[6];
    const float* b2   = (const float*)d_in[7];
    const float* W2r  = (const float*)d_in[8];
    const float* W3l  = (const float*)d_in[9];
    const float* b3   = (const float*)d_in[10];
    const float* W3r  = (const float*)d_in[11];
    const float* Wfc1 = (const float*)d_in[12];
    const float* bfc1 = (const float*)d_in[13];
    const float* Wfc2 = (const float*)d_in[14];
    const float* bfc2 = (const float*)d_in[15];
    float* out = (float*)d_out;

    // Workspace layout (256 B aligned slices)
    char* ws = (char*)d_ws;
    size_t o = 0;
    auto alloc = [&](size_t bytes) { char* p = ws + o; o += (bytes + 255) & ~(size_t)255; return p; };
    int*   bcnt    = (int*)alloc((size_t)NB * 4);
    int*   bbase   = (int*)alloc(((size_t)NB + 1) * 4);
    int*   bcursor = (int*)alloc((size_t)NB * 4);
    unsigned int* entries = (unsigned int*)alloc((size_t)E * 4);
    int*   rowptr  = (int*)alloc(((size_t)N + 1) * 4);
    int*   csr     = (int*)alloc((size_t)E * 4);
    float* mean1   = (float*)alloc((size_t)N * 4);
    float* h1      = (float*)alloc((size_t)N * HID * 4);   // reused as h3
    float* meanb   = (float*)alloc((size_t)N * HID * 4);
    float* h2      = (float*)alloc((size_t)N * HID * 4);
    float* psum    = (float*)alloc((size_t)NGRAPHS * HID * 4);
    int*   gcnt    = (int*)alloc((size_t)NGRAPHS * 4);
    int*   flags   = (int*)alloc(16);
    float* h3 = h1;

    // Zero what must be zero (ws is poisoned 0xAA before every call)
    hipMemsetAsync(bcnt, 0, (size_t)NB * 4, stream);
    hipMemsetAsync(psum, 0, (size_t)NGRAPHS * HID * 4 + 256, stream);  // psum + gcnt (adjacent)

    // Index dtype detection
    detect_kernel<<<1, 64, 0, stream>>>(edge, batch, flags, E2, N, NGRAPHS);

    // Binned CSR build: count -> scan -> scatter -> per-bucket finalize
    const int nblk = (E + EPB - 1) / EPB;   // 196
    bin_count_kernel<<<nblk, 256, NB * 4, stream>>>(edge, flags, bcnt, E, NB);
    bin_scan_kernel<<<1, 1024, 0, stream>>>(bcnt, bbase, bcursor, NB);
    bin_scatter_kernel<<<nblk, 256, 2 * NB * 4, stream>>>(edge, flags, bcursor, entries, E, NB);
    csr_finalize_kernel<<<NB, 256, 0, stream>>>(entries, bbase, rowptr, csr, N, NB);

    // Layer 1
    gather1_kernel<<<(N + 255) / 256, 256, 0, stream>>>(rowptr, csr, x, mean1, N);
    node1_kernel<<<((size_t)N * HID + 255) / 256, 256, 0, stream>>>(x, mean1, W1l, b1, W1r, h1, N);

    // Layer 2
    gather_mean_kernel<<<(N + 15) / 16, 256, 0, stream>>>(rowptr, csr, h1, meanb, N);
    node_layer_kernel<<<1024, 256, 0, stream>>>(h1, meanb, W2l, b2, W2r, h2, N);

    // Layer 3
    gather_mean_kernel<<<(N + 15) / 16, 256, 0, stream>>>(rowptr, csr, h2, meanb, N);
    node_layer_kernel<<<1024, 256, 0, stream>>>(h2, meanb, W3l, b3, W3r, h3, N);

    // Pool + FC head
    {
        int nodesPerWave = 64;
        int waves = (N + nodesPerWave - 1) / nodesPerWave;
        int threads = waves * 64;
        pool_kernel<<<(threads + 255) / 256, 256, 0, stream>>>(h3, batch, flags, psum, gcnt,
                                                               N, nodesPerWave);
    }
    fc_kernel<<<NGRAPHS, 64, 0, stream>>>(psum, gcnt, Wfc1, bfc1, Wfc2, bfc2, out);
}

// Round 6
// 316.853 us; speedup vs baseline: 3.1016x; 1.0838x over previous
//
#include <hip/hip_runtime.h>
#include <hip/hip_bf16.h>

#define HID 64
#define NGRAPHS 64
#define BUCKET 64        // nodes per bucket (dst >> 6)
#define EPB 4096         // edges per block in bin_count / bin_scatter
#define NL_BLOCKS 512    // node_layer grid (2048 waves)

// ---------------------------------------------------------------------------
// Detect whether edge_index / batch are int64 or int32 on device.
// Samples int64 reads within the first half of each buffer (in-bounds for
// either dtype). int32 data read as int64 pairs random indices -> virtually
// never all in [0, range). flags[0]=edge is 64-bit, flags[1]=batch is 64-bit.
// ---------------------------------------------------------------------------
__global__ __launch_bounds__(64) void detect_kernel(const void* edge, const void* batch,
                                                    int* flags, int E2, int N, int G) {
    int lane = threadIdx.x;
    int half = E2 / 2;
    int stride = half / 64; if (stride < 1) stride = 1;
    int j = lane * stride; if (j >= half) j = half - 1;
    long long v = ((const long long*)edge)[j];
    bool ok = (v >= 0 && v < (long long)N);
    unsigned long long m = __ballot(ok);
    if (lane == 0) flags[0] = (m == ~0ULL) ? 1 : 0;
    int halfB = N / 2;
    int strideB = halfB / 64; if (strideB < 1) strideB = 1;
    int jb = lane * strideB; if (jb >= halfB) jb = halfB - 1;
    long long vb = ((const long long*)batch)[jb];
    bool okb = (vb >= 0 && vb < (long long)G);
    unsigned long long mb = __ballot(okb);
    if (lane == 0) flags[1] = (mb == ~0ULL) ? 1 : 0;
}

__device__ __forceinline__ int idx_at(const void* p, int i, bool is64) {
    return is64 ? (int)((const long long*)p)[i] : ((const int*)p)[i];
}

// ---------------------------------------------------------------------------
// Bucket histogram: LDS-local counts, one global add per (block, bucket).
// ---------------------------------------------------------------------------
__global__ __launch_bounds__(256) void bin_count_kernel(const void* edge, const int* __restrict__ flags,
                                                        int* __restrict__ bcnt, int E, int NB) {
    extern __shared__ int hist[];   // NB ints
    for (int i = threadIdx.x; i < NB; i += 256) hist[i] = 0;
    __syncthreads();
    bool is64 = flags[0] != 0;
    int start = blockIdx.x * EPB;
    int end = start + EPB; if (end > E) end = E;
    for (int e = start + threadIdx.x; e < end; e += 256) {
        int d = idx_at(edge, E + e, is64);
        atomicAdd(&hist[d >> 6], 1);
    }
    __syncthreads();
    for (int i = threadIdx.x; i < NB; i += 256) {
        int h = hist[i];
        if (h) atomicAdd(&bcnt[i], h);
    }
}

// ---------------------------------------------------------------------------
// Exclusive scan of bucket counts (NB <= 1024): bbase[NB+1], bcursor init.
// ---------------------------------------------------------------------------
__global__ __launch_bounds__(1024) void bin_scan_kernel(const int* __restrict__ bcnt,
                                                        int* __restrict__ bbase,
                                                        int* __restrict__ bcursor, int NB) {
    __shared__ int s[1024];
    int t = threadIdx.x;
    int v = (t < NB) ? bcnt[t] : 0;
    s[t] = v;
    __syncthreads();
    for (int off = 1; off < 1024; off <<= 1) {
        int tmp = (t >= off) ? s[t - off] : 0;
        __syncthreads();
        s[t] += tmp;
        __syncthreads();
    }
    if (t < NB) {
        int ex = s[t] - v;
        bbase[t] = ex;
        bcursor[t] = ex;
        if (t == NB - 1) bbase[NB] = s[t];
    }
}

// ---------------------------------------------------------------------------
// Bucket scatter: per-block histogram -> one range reservation per bucket ->
// contiguous packed-entry appends. entry = (src << 6) | (dst & 63).
// ---------------------------------------------------------------------------
__global__ __launch_bounds__(256) void bin_scatter_kernel(const void* edge, const int* __restrict__ flags,
                                                          int* __restrict__ bcursor,
                                                          unsigned int* __restrict__ entries,
                                                          int E, int NB) {
    extern __shared__ int lds[];    // hist[NB] + base[NB]
    int* hist = lds;
    int* base = lds + NB;
    for (int i = threadIdx.x; i < NB; i += 256) hist[i] = 0;
    __syncthreads();
    bool is64 = flags[0] != 0;
    int start = blockIdx.x * EPB;
    int end = start + EPB; if (end > E) end = E;
    for (int e = start + threadIdx.x; e < end; e += 256) {
        int d = idx_at(edge, E + e, is64);
        atomicAdd(&hist[d >> 6], 1);
    }
    __syncthreads();
    for (int i = threadIdx.x; i < NB; i += 256) {
        int h = hist[i];
        base[i] = h ? atomicAdd(&bcursor[i], h) : 0;
    }
    __syncthreads();
    for (int i = threadIdx.x; i < NB; i += 256) hist[i] = 0;  // reuse as local cursor
    __syncthreads();
    for (int e = start + threadIdx.x; e < end; e += 256) {
        int srcv = idx_at(edge, e, is64);
        int d = idx_at(edge, E + e, is64);
        int b = d >> 6;
        int lo = atomicAdd(&hist[b], 1);
        entries[base[b] + lo] = ((unsigned int)srcv << 6) | (unsigned int)(d & 63);
    }
}

// ---------------------------------------------------------------------------
// Per-bucket CSR finalize: one block per bucket. Histogram the bucket's 64
// destinations, wave-prefix-scan, write rowptr (coalesced) and scatter src
// into csr within the bucket's contiguous window (high cacheline reuse).
// ---------------------------------------------------------------------------
__global__ __launch_bounds__(256) void csr_finalize_kernel(const unsigned int* __restrict__ entries,
                                                           const int* __restrict__ bbase,
                                                           int* __restrict__ rowptr,
                                                           int* __restrict__ csr,
                                                           int N, int NB) {
    __shared__ int hist[BUCKET];
    __shared__ int lstart[BUCKET];
    __shared__ int lcur[BUCKET];
    int t = threadIdx.x;
    int b = blockIdx.x;
    if (t < BUCKET) { hist[t] = 0; lcur[t] = 0; }
    __syncthreads();
    int r0 = bbase[b], r1 = bbase[b + 1];
    for (int j = r0 + t; j < r1; j += 256) {
        atomicAdd(&hist[entries[j] & 63u], 1);
    }
    __syncthreads();
    if (t < BUCKET) {  // wave 0: 64-lane inclusive shuffle scan -> exclusive
        int v = hist[t];
        int s = v;
#pragma unroll
        for (int off = 1; off < 64; off <<= 1) {
            int u = __shfl_up(s, off);
            if (t >= off) s += u;
        }
        lstart[t] = s - v;
        int node = b * BUCKET + t;
        if (node < N) rowptr[node] = r0 + s - v;
        if (b == NB - 1 && t == 63) rowptr[N] = r1;
    }
    __syncthreads();
    for (int j = r0 + t; j < r1; j += 256) {
        unsigned int en = entries[j];
        int dl = (int)(en & 63u);
        int p = atomicAdd(&lcur[dl], 1);
        csr[r0 + lstart[dl] + p] = (int)(en >> 6);
    }
}

// ---------------------------------------------------------------------------
// Layer 1 aggregation (scalar feature): gather mean of x over neighbors.
// ---------------------------------------------------------------------------
__global__ __launch_bounds__(256) void gather1_kernel(const int* __restrict__ rowptr,
                                                      const int* __restrict__ csr,
                                                      const float* __restrict__ x,
                                                      float* __restrict__ mean1, int N) {
    int i = blockIdx.x * blockDim.x + threadIdx.x;
    if (i >= N) return;
    int r0 = rowptr[i], r1 = rowptr[i + 1];
    float s = 0.0f;
    for (int j = r0; j < r1; ++j) s += x[csr[j]];
    mean1[i] = (r1 > r0) ? s / (float)(r1 - r0) : 0.0f;
}

// Layer 1 node transform: h1[i][f] = relu(mean1_i*W1l[f] + b1[f] + x_i*W1r[f]) + x_i
__global__ __launch_bounds__(256) void node1_kernel(const float* __restrict__ x,
                                                    const float* __restrict__ mean1,
                                                    const float* __restrict__ W1l,
                                                    const float* __restrict__ b1,
                                                    const float* __restrict__ W1r,
                                                    float* __restrict__ h1, int N) {
    int tid = blockIdx.x * blockDim.x + threadIdx.x;
    if (tid >= N * HID) return;
    int i = tid >> 6, f = tid & 63;
    float xv = x[i];
    float v = mean1[i] * W1l[f] + b1[f] + xv * W1r[f];
    v = v > 0.0f ? v : 0.0f;
    h1[tid] = v + xv;
}

// ---------------------------------------------------------------------------
// Layers 2/3 aggregation via gather: 16 lanes per node, float4 per lane.
// Writes the MEAN row directly (degree = rowptr diff). No atomics.
// ---------------------------------------------------------------------------
__global__ __launch_bounds__(256) void gather_mean_kernel(const int* __restrict__ rowptr,
                                                          const int* __restrict__ csr,
                                                          const float* __restrict__ h,
                                                          float* __restrict__ mean, int N) {
    int grp = threadIdx.x >> 4;      // 16 groups per block
    int l = threadIdx.x & 15;        // lane within group -> one float4 of the row
    int i = blockIdx.x * 16 + grp;
    if (i >= N) return;
    int r0 = rowptr[i], r1 = rowptr[i + 1];
    float4 acc = make_float4(0.f, 0.f, 0.f, 0.f);
    for (int j = r0; j < r1; ++j) {
        int s = csr[j];
        const float4 v = *(const float4*)(h + (size_t)s * HID + l * 4);
        acc.x += v.x; acc.y += v.y; acc.z += v.z; acc.w += v.w;
    }
    float inv = (r1 > r0) ? 1.0f / (float)(r1 - r0) : 0.0f;
    acc.x *= inv; acc.y *= inv; acc.z *= inv; acc.w *= inv;
    *(float4*)(mean + (size_t)i * HID + l * 4) = acc;
}

// ---------------------------------------------------------------------------
// Layers 2/3 node transform — register-weight / scalar-row version.
// Lane = output feature f; Wl[:,f], Wr[:,f] preloaded into VGPRs (128 regs,
// amortized over ~24 nodes/wave). Node index is wave-uniform (readfirstlane)
// so mean/hprev row element loads scalarize to s_load feeding v_fma's SGPR
// operand. Zero LDS; inner loop is pure VALU (2 v_fma per k).
// hout[i][f] = relu( sum_k mean[i][k]*Wl[k][f] + hprev[i][k]*Wr[k][f] + b[f] ) + hprev[i][f]
// ---------------------------------------------------------------------------
__global__ __launch_bounds__(256) void node_layer_kernel(const float* __restrict__ hprev,
                                                         const float* __restrict__ mean,
                                                         const float* __restrict__ Wl,
                                                         const float* __restrict__ bvec,
                                                         const float* __restrict__ Wr,
                                                         float* __restrict__ hout,
                                                         int N, int nwaves) {
    int f = threadIdx.x & 63;
    int wid = (blockIdx.x * blockDim.x + threadIdx.x) >> 6;
    float wl[HID], wr[HID];
#pragma unroll
    for (int k = 0; k < HID; ++k) {
        wl[k] = Wl[k * HID + f];
        wr[k] = Wr[k * HID + f];
    }
    float bf = bvec[f];
    for (int i = wid; i < N; i += nwaves) {
        int iu = __builtin_amdgcn_readfirstlane(i);
        const float* mrow = mean + (size_t)iu * HID;
        const float* hrow = hprev + (size_t)iu * HID;
        float hpv = hrow[f];          // per-lane vector load (coalesced row)
        float acc = bf;
#pragma unroll
        for (int k = 0; k < HID; ++k) {
            acc = fmaf(mrow[k], wl[k], acc);   // mrow[k]: wave-uniform -> s_load
            acc = fmaf(hrow[k], wr[k], acc);
        }
        float r = acc > 0.0f ? acc : 0.0f;
        hout[(size_t)iu * HID + f] = r + hpv;
    }
}

// ---------------------------------------------------------------------------
// Global mean pool: batch is sorted -> run-length accumulate per wave.
// ---------------------------------------------------------------------------
__global__ __launch_bounds__(256) void pool_kernel(const float* __restrict__ h,
                                                   const void* batch,
                                                   const int* __restrict__ flags,
                                                   float* __restrict__ psum,
                                                   int* __restrict__ gcnt,
                                                   int N, int nodesPerWave) {
    int wave = (blockIdx.x * blockDim.x + threadIdx.x) >> 6;
    int f = threadIdx.x & 63;
    int start = wave * nodesPerWave;
    if (start >= N) return;
    bool is64 = flags[1] != 0;
    int end = start + nodesPerWave;
    if (end > N) end = N;
    int g = idx_at(batch, start, is64);
    float acc = 0.0f;
    int c = 0;
    for (int i = start; i < end; ++i) {
        int gi = idx_at(batch, i, is64);
        if (gi != g) {
            atomicAdd(&psum[g * HID + f], acc);
            if (f == 0) atomicAdd(&gcnt[g], c);
            acc = 0.0f; c = 0; g = gi;
        }
        acc += h[(size_t)i * HID + f];
        c++;
    }
    atomicAdd(&psum[g * HID + f], acc);
    if (f == 0) atomicAdd(&gcnt[g], c);
}

// ---------------------------------------------------------------------------
// FC head: one block (64 threads) per graph.
// ---------------------------------------------------------------------------
__global__ __launch_bounds__(64) void fc_kernel(const float* __restrict__ psum,
                                                const int* __restrict__ gcnt,
                                                const float* __restrict__ Wfc1,
                                                const float* __restrict__ bfc1,
                                                const float* __restrict__ Wfc2,
                                                const float* __restrict__ bfc2,
                                                float* __restrict__ out) {
    int g = blockIdx.x;
    int t = threadIdx.x;
    __shared__ float mean[HID];
    float c = fmaxf((float)gcnt[g], 1.0f);
    mean[t] = psum[g * HID + t] / c;
    __syncthreads();
    float v = 0.0f;
    if (t < 32) {
        float acc = bfc1[t];
#pragma unroll
        for (int k = 0; k < HID; ++k) acc += mean[k] * Wfc1[k * 32 + t];
        float hcc = acc > 0.0f ? acc : 0.0f;
        v = hcc * Wfc2[t];
    }
#pragma unroll
    for (int off = 32; off >= 1; off >>= 1) v += __shfl_down(v, off);
    if (t == 0) out[g] = v + bfc2[0];
}

extern "C" void kernel_launch(void* const* d_in, const int* in_sizes, int n_in,
                              void* d_out, int out_size, void* d_ws, size_t ws_size,
                              hipStream_t stream) {
    const int N = in_sizes[0];       // 50000
    const int E2 = in_sizes[1];      // 2*E
    const int E = E2 / 2;
    const int NB = (N + BUCKET - 1) / BUCKET;   // 782

    const float* x    = (const float*)d_in[0];
    const void*  edge = d_in[1];
    const void*  batch= d_in[2];
    const float* W1l  = (const float*)d_in[3];
    const float* b1   = (const float*)d_in[4];
    const float* W1r  = (const float*)d_in[5];
    const float* W2l  = (const float*)d_in[6];
    const float* b2   = (const float*)d_in[7];
    const float* W2r  = (const float*)d_in[8];
    const float* W3l  = (const float*)d_in[9];
    const float* b3   = (const float*)d_in[10];
    const float* W3r  = (const float*)d_in[11];
    const float* Wfc1 = (const float*)d_in[12];
    const float* bfc1 = (const float*)d_in[13];
    const float* Wfc2 = (const float*)d_in[14];
    const float* bfc2 = (const float*)d_in[15];
    float* out = (float*)d_out;

    // Workspace layout (256 B aligned slices)
    char* ws = (char*)d_ws;
    size_t o = 0;
    auto alloc = [&](size_t bytes) { char* p = ws + o; o += (bytes + 255) & ~(size_t)255; return p; };
    int*   bcnt    = (int*)alloc((size_t)NB * 4);
    int*   bbase   = (int*)alloc(((size_t)NB + 1) * 4);
    int*   bcursor = (int*)alloc((size_t)NB * 4);
    unsigned int* entries = (unsigned int*)alloc((size_t)E * 4);
    int*   rowptr  = (int*)alloc(((size_t)N + 1) * 4);
    int*   csr     = (int*)alloc((size_t)E * 4);
    float* mean1   = (float*)alloc((size_t)N * 4);
    float* h1      = (float*)alloc((size_t)N * HID * 4);   // reused as h3
    float* meanb   = (float*)alloc((size_t)N * HID * 4);
    float* h2      = (float*)alloc((size_t)N * HID * 4);
    float* psum    = (float*)alloc((size_t)NGRAPHS * HID * 4);
    int*   gcnt    = (int*)alloc((size_t)NGRAPHS * 4);
    int*   flags   = (int*)alloc(16);
    float* h3 = h1;

    // Zero what must be zero (ws is poisoned 0xAA before every call)
    hipMemsetAsync(bcnt, 0, (size_t)NB * 4, stream);
    hipMemsetAsync(psum, 0, (size_t)NGRAPHS * HID * 4 + 256, stream);  // psum + gcnt (adjacent)

    // Index dtype detection
    detect_kernel<<<1, 64, 0, stream>>>(edge, batch, flags, E2, N, NGRAPHS);

    // Binned CSR build: count -> scan -> scatter -> per-bucket finalize
    const int nblk = (E + EPB - 1) / EPB;   // 196
    bin_count_kernel<<<nblk, 256, NB * 4, stream>>>(edge, flags, bcnt, E, NB);
    bin_scan_kernel<<<1, 1024, 0, stream>>>(bcnt, bbase, bcursor, NB);
    bin_scatter_kernel<<<nblk, 256, 2 * NB * 4, stream>>>(edge, flags, bcursor, entries, E, NB);
    csr_finalize_kernel<<<NB, 256, 0, stream>>>(entries, bbase, rowptr, csr, N, NB);

    // Layer 1
    gather1_kernel<<<(N + 255) / 256, 256, 0, stream>>>(rowptr, csr, x, mean1, N);
    node1_kernel<<<((size_t)N * HID + 255) / 256, 256, 0, stream>>>(x, mean1, W1l, b1, W1r, h1, N);

    const int nlWaves = NL_BLOCKS * 4;   // 256-thread blocks = 4 waves each

    // Layer 2
    gather_mean_kernel<<<(N + 15) / 16, 256, 0, stream>>>(rowptr, csr, h1, meanb, N);
    node_layer_kernel<<<NL_BLOCKS, 256, 0, stream>>>(h1, meanb, W2l, b2, W2r, h2, N, nlWaves);

    // Layer 3
    gather_mean_kernel<<<(N + 15) / 16, 256, 0, stream>>>(rowptr, csr, h2, meanb, N);
    node_layer_kernel<<<NL_BLOCKS, 256, 0, stream>>>(h2, meanb, W3l, b3, W3r, h3, N, nlWaves);

    // Pool + FC head
    {
        int nodesPerWave = 64;
        int waves = (N + nodesPerWave - 1) / nodesPerWave;
        int threads = waves * 64;
        pool_kernel<<<(threads + 255) / 256, 256, 0, stream>>>(h3, batch, flags, psum, gcnt,
                                                               N, nodesPerWave);
    }
    fc_kernel<<<NGRAPHS, 64, 0, stream>>>(psum, gcnt, Wfc1, bfc1, Wfc2, bfc2, out);
}

// Round 7
// 299.485 us; speedup vs baseline: 3.2815x; 1.0580x over previous
//
#include <hip/hip_runtime.h>
#include <hip/hip_bf16.h>

#define HID 64
#define NGRAPHS 64
#define BUCKET 64        // nodes per bucket (dst >> 6)
#define EPB 4096         // edges per block in bin_count / bin_scatter
#define NL_BLOCKS 512    // node_layer grid (2048 waves = one resident cohort)

// ---------------------------------------------------------------------------
// Detect whether edge_index / batch are int64 or int32 on device.
// ---------------------------------------------------------------------------
__global__ __launch_bounds__(64) void detect_kernel(const void* edge, const void* batch,
                                                    int* flags, int E2, int N, int G) {
    int lane = threadIdx.x;
    int half = E2 / 2;
    int stride = half / 64; if (stride < 1) stride = 1;
    int j = lane * stride; if (j >= half) j = half - 1;
    long long v = ((const long long*)edge)[j];
    bool ok = (v >= 0 && v < (long long)N);
    unsigned long long m = __ballot(ok);
    if (lane == 0) flags[0] = (m == ~0ULL) ? 1 : 0;
    int halfB = N / 2;
    int strideB = halfB / 64; if (strideB < 1) strideB = 1;
    int jb = lane * strideB; if (jb >= halfB) jb = halfB - 1;
    long long vb = ((const long long*)batch)[jb];
    bool okb = (vb >= 0 && vb < (long long)G);
    unsigned long long mb = __ballot(okb);
    if (lane == 0) flags[1] = (mb == ~0ULL) ? 1 : 0;
}

__device__ __forceinline__ int idx_at(const void* p, int i, bool is64) {
    return is64 ? (int)((const long long*)p)[i] : ((const int*)p)[i];
}

// ---------------------------------------------------------------------------
// Bucket histogram: LDS-local counts, one global add per (block, bucket).
// ---------------------------------------------------------------------------
__global__ __launch_bounds__(256) void bin_count_kernel(const void* edge, const int* __restrict__ flags,
                                                        int* __restrict__ bcnt, int E, int NB) {
    extern __shared__ int hist[];   // NB ints
    for (int i = threadIdx.x; i < NB; i += 256) hist[i] = 0;
    __syncthreads();
    bool is64 = flags[0] != 0;
    int start = blockIdx.x * EPB;
    int end = start + EPB; if (end > E) end = E;
    for (int e = start + threadIdx.x; e < end; e += 256) {
        int d = idx_at(edge, E + e, is64);
        atomicAdd(&hist[d >> 6], 1);
    }
    __syncthreads();
    for (int i = threadIdx.x; i < NB; i += 256) {
        int h = hist[i];
        if (h) atomicAdd(&bcnt[i], h);
    }
}

// ---------------------------------------------------------------------------
// Exclusive scan of bucket counts (NB <= 1024): bbase[NB+1], bcursor init.
// ---------------------------------------------------------------------------
__global__ __launch_bounds__(1024) void bin_scan_kernel(const int* __restrict__ bcnt,
                                                        int* __restrict__ bbase,
                                                        int* __restrict__ bcursor, int NB) {
    __shared__ int s[1024];
    int t = threadIdx.x;
    int v = (t < NB) ? bcnt[t] : 0;
    s[t] = v;
    __syncthreads();
    for (int off = 1; off < 1024; off <<= 1) {
        int tmp = (t >= off) ? s[t - off] : 0;
        __syncthreads();
        s[t] += tmp;
        __syncthreads();
    }
    if (t < NB) {
        int ex = s[t] - v;
        bbase[t] = ex;
        bcursor[t] = ex;
        if (t == NB - 1) bbase[NB] = s[t];
    }
}

// ---------------------------------------------------------------------------
// Bucket scatter: per-block histogram -> one range reservation per bucket ->
// contiguous packed-entry appends. entry = (src << 6) | (dst & 63).
// ---------------------------------------------------------------------------
__global__ __launch_bounds__(256) void bin_scatter_kernel(const void* edge, const int* __restrict__ flags,
                                                          int* __restrict__ bcursor,
                                                          unsigned int* __restrict__ entries,
                                                          int E, int NB) {
    extern __shared__ int lds[];    // hist[NB] + base[NB]
    int* hist = lds;
    int* base = lds + NB;
    for (int i = threadIdx.x; i < NB; i += 256) hist[i] = 0;
    __syncthreads();
    bool is64 = flags[0] != 0;
    int start = blockIdx.x * EPB;
    int end = start + EPB; if (end > E) end = E;
    for (int e = start + threadIdx.x; e < end; e += 256) {
        int d = idx_at(edge, E + e, is64);
        atomicAdd(&hist[d >> 6], 1);
    }
    __syncthreads();
    for (int i = threadIdx.x; i < NB; i += 256) {
        int h = hist[i];
        base[i] = h ? atomicAdd(&bcursor[i], h) : 0;
    }
    __syncthreads();
    for (int i = threadIdx.x; i < NB; i += 256) hist[i] = 0;  // reuse as local cursor
    __syncthreads();
    for (int e = start + threadIdx.x; e < end; e += 256) {
        int srcv = idx_at(edge, e, is64);
        int d = idx_at(edge, E + e, is64);
        int b = d >> 6;
        int lo = atomicAdd(&hist[b], 1);
        entries[base[b] + lo] = ((unsigned int)srcv << 6) | (unsigned int)(d & 63);
    }
}

// ---------------------------------------------------------------------------
// Per-bucket CSR finalize: histogram bucket's 64 dests, wave scan, write
// rowptr + csr within the bucket's contiguous window.
// ---------------------------------------------------------------------------
__global__ __launch_bounds__(256) void csr_finalize_kernel(const unsigned int* __restrict__ entries,
                                                           const int* __restrict__ bbase,
                                                           int* __restrict__ rowptr,
                                                           int* __restrict__ csr,
                                                           int N, int NB) {
    __shared__ int hist[BUCKET];
    __shared__ int lstart[BUCKET];
    __shared__ int lcur[BUCKET];
    int t = threadIdx.x;
    int b = blockIdx.x;
    if (t < BUCKET) { hist[t] = 0; lcur[t] = 0; }
    __syncthreads();
    int r0 = bbase[b], r1 = bbase[b + 1];
    for (int j = r0 + t; j < r1; j += 256) {
        atomicAdd(&hist[entries[j] & 63u], 1);
    }
    __syncthreads();
    if (t < BUCKET) {  // wave 0: 64-lane inclusive shuffle scan -> exclusive
        int v = hist[t];
        int s = v;
#pragma unroll
        for (int off = 1; off < 64; off <<= 1) {
            int u = __shfl_up(s, off);
            if (t >= off) s += u;
        }
        lstart[t] = s - v;
        int node = b * BUCKET + t;
        if (node < N) rowptr[node] = r0 + s - v;
        if (b == NB - 1 && t == 63) rowptr[N] = r1;
    }
    __syncthreads();
    for (int j = r0 + t; j < r1; j += 256) {
        unsigned int en = entries[j];
        int dl = (int)(en & 63u);
        int p = atomicAdd(&lcur[dl], 1);
        csr[r0 + lstart[dl] + p] = (int)(en >> 6);
    }
}

// ---------------------------------------------------------------------------
// Layer 1 fused: phase 1 = thread-per-node scalar neighbor mean into LDS;
// phase 2 = 64-threads-per-node transform.
// h1[i][f] = relu(mean1_i*W1l[f] + b1[f] + x_i*W1r[f]) + x_i
// ---------------------------------------------------------------------------
__global__ __launch_bounds__(256) void layer1_kernel(const int* __restrict__ rowptr,
                                                     const int* __restrict__ csr,
                                                     const float* __restrict__ x,
                                                     const float* __restrict__ W1l,
                                                     const float* __restrict__ b1,
                                                     const float* __restrict__ W1r,
                                                     float* __restrict__ h1, int N) {
    __shared__ float smean[256];
    __shared__ float sx[256];
    int t = threadIdx.x;
    int i0 = blockIdx.x * 256;
    int i = i0 + t;
    if (i < N) {
        int r0 = rowptr[i], r1 = rowptr[i + 1];
        float s = 0.0f;
        for (int j = r0; j < r1; ++j) s += x[csr[j]];
        smean[t] = (r1 > r0) ? s / (float)(r1 - r0) : 0.0f;
        sx[t] = x[i];
    }
    __syncthreads();
    int f = t & 63;
    int sub = t >> 6;   // 0..3
    float wlf = W1l[f], bf = b1[f], wrf = W1r[f];
    for (int it = 0; it < 64; ++it) {
        int nl = it * 4 + sub;
        int node = i0 + nl;
        if (node < N) {
            float mv = smean[nl], xv = sx[nl];
            float v = fmaf(mv, wlf, fmaf(xv, wrf, bf));
            v = v > 0.0f ? v : 0.0f;
            h1[(size_t)node * HID + f] = v + xv;
        }
    }
}

// ---------------------------------------------------------------------------
// Layers 2/3 aggregation via gather: 16 lanes per node, float4 per lane.
// 4x manual unroll with independent accumulators for memory-level parallelism.
// ---------------------------------------------------------------------------
__global__ __launch_bounds__(256) void gather_mean_kernel(const int* __restrict__ rowptr,
                                                          const int* __restrict__ csr,
                                                          const float* __restrict__ h,
                                                          float* __restrict__ mean, int N) {
    int grp = threadIdx.x >> 4;      // 16 groups per block
    int l = threadIdx.x & 15;        // lane within group -> one float4 of the row
    int i = blockIdx.x * 16 + grp;
    if (i >= N) return;
    int r0 = rowptr[i], r1 = rowptr[i + 1];
    float4 a0 = make_float4(0.f, 0.f, 0.f, 0.f);
    float4 a1 = make_float4(0.f, 0.f, 0.f, 0.f);
    float4 a2 = make_float4(0.f, 0.f, 0.f, 0.f);
    float4 a3 = make_float4(0.f, 0.f, 0.f, 0.f);
    int j = r0;
    for (; j + 4 <= r1; j += 4) {
        int s0 = csr[j], s1 = csr[j + 1], s2 = csr[j + 2], s3 = csr[j + 3];
        const float4 v0 = *(const float4*)(h + (size_t)s0 * HID + l * 4);
        const float4 v1 = *(const float4*)(h + (size_t)s1 * HID + l * 4);
        const float4 v2 = *(const float4*)(h + (size_t)s2 * HID + l * 4);
        const float4 v3 = *(const float4*)(h + (size_t)s3 * HID + l * 4);
        a0.x += v0.x; a0.y += v0.y; a0.z += v0.z; a0.w += v0.w;
        a1.x += v1.x; a1.y += v1.y; a1.z += v1.z; a1.w += v1.w;
        a2.x += v2.x; a2.y += v2.y; a2.z += v2.z; a2.w += v2.w;
        a3.x += v3.x; a3.y += v3.y; a3.z += v3.z; a3.w += v3.w;
    }
    for (; j < r1; ++j) {
        int s = csr[j];
        const float4 v = *(const float4*)(h + (size_t)s * HID + l * 4);
        a0.x += v.x; a0.y += v.y; a0.z += v.z; a0.w += v.w;
    }
    float4 acc;
    acc.x = (a0.x + a1.x) + (a2.x + a3.x);
    acc.y = (a0.y + a1.y) + (a2.y + a3.y);
    acc.z = (a0.z + a1.z) + (a2.z + a3.z);
    acc.w = (a0.w + a1.w) + (a2.w + a3.w);
    float inv = (r1 > r0) ? 1.0f / (float)(r1 - r0) : 0.0f;
    acc.x *= inv; acc.y *= inv; acc.z *= inv; acc.w *= inv;
    *(float4*)(mean + (size_t)i * HID + l * 4) = acc;
}

// ---------------------------------------------------------------------------
// Layers 2/3 node transform — register-weight / scalar-row version.
// Lane = output feature f; Wl[:,f], Wr[:,f] in VGPRs; node index wave-uniform
// so mean/hprev row loads scalarize to s_load feeding v_fma.
// ---------------------------------------------------------------------------
__global__ __launch_bounds__(256) void node_layer_kernel(const float* __restrict__ hprev,
                                                         const float* __restrict__ mean,
                                                         const float* __restrict__ Wl,
                                                         const float* __restrict__ bvec,
                                                         const float* __restrict__ Wr,
                                                         float* __restrict__ hout,
                                                         int N, int nwaves) {
    int f = threadIdx.x & 63;
    int wid = (blockIdx.x * blockDim.x + threadIdx.x) >> 6;
    float wl[HID], wr[HID];
#pragma unroll
    for (int k = 0; k < HID; ++k) {
        wl[k] = Wl[k * HID + f];
        wr[k] = Wr[k * HID + f];
    }
    float bf = bvec[f];
    for (int i = wid; i < N; i += nwaves) {
        int iu = __builtin_amdgcn_readfirstlane(i);
        const float* mrow = mean + (size_t)iu * HID;
        const float* hrow = hprev + (size_t)iu * HID;
        float hpv = hrow[f];
        float acc = bf;
#pragma unroll
        for (int k = 0; k < HID; ++k) {
            acc = fmaf(mrow[k], wl[k], acc);
            acc = fmaf(hrow[k], wr[k], acc);
        }
        float r = acc > 0.0f ? acc : 0.0f;
        hout[(size_t)iu * HID + f] = r + hpv;
    }
}

// ---------------------------------------------------------------------------
// Global mean pool: batch is sorted -> run-length accumulate per wave.
// ---------------------------------------------------------------------------
__global__ __launch_bounds__(256) void pool_kernel(const float* __restrict__ h,
                                                   const void* batch,
                                                   const int* __restrict__ flags,
                                                   float* __restrict__ psum,
                                                   int* __restrict__ gcnt,
                                                   int N, int nodesPerWave) {
    int wave = (blockIdx.x * blockDim.x + threadIdx.x) >> 6;
    int f = threadIdx.x & 63;
    int start = wave * nodesPerWave;
    if (start >= N) return;
    bool is64 = flags[1] != 0;
    int end = start + nodesPerWave;
    if (end > N) end = N;
    int g = idx_at(batch, start, is64);
    float acc = 0.0f;
    int c = 0;
    for (int i = start; i < end; ++i) {
        int gi = idx_at(batch, i, is64);
        if (gi != g) {
            atomicAdd(&psum[g * HID + f], acc);
            if (f == 0) atomicAdd(&gcnt[g], c);
            acc = 0.0f; c = 0; g = gi;
        }
        acc += h[(size_t)i * HID + f];
        c++;
    }
    atomicAdd(&psum[g * HID + f], acc);
    if (f == 0) atomicAdd(&gcnt[g], c);
}

// ---------------------------------------------------------------------------
// FC head: one block (64 threads) per graph.
// ---------------------------------------------------------------------------
__global__ __launch_bounds__(64) void fc_kernel(const float* __restrict__ psum,
                                                const int* __restrict__ gcnt,
                                                const float* __restrict__ Wfc1,
                                                const float* __restrict__ bfc1,
                                                const float* __restrict__ Wfc2,
                                                const float* __restrict__ bfc2,
                                                float* __restrict__ out) {
    int g = blockIdx.x;
    int t = threadIdx.x;
    __shared__ float mean[HID];
    float c = fmaxf((float)gcnt[g], 1.0f);
    mean[t] = psum[g * HID + t] / c;
    __syncthreads();
    float v = 0.0f;
    if (t < 32) {
        float acc = bfc1[t];
#pragma unroll
        for (int k = 0; k < HID; ++k) acc += mean[k] * Wfc1[k * 32 + t];
        float hcc = acc > 0.0f ? acc : 0.0f;
        v = hcc * Wfc2[t];
    }
#pragma unroll
    for (int off = 32; off >= 1; off >>= 1) v += __shfl_down(v, off);
    if (t == 0) out[g] = v + bfc2[0];
}

extern "C" void kernel_launch(void* const* d_in, const int* in_sizes, int n_in,
                              void* d_out, int out_size, void* d_ws, size_t ws_size,
                              hipStream_t stream) {
    const int N = in_sizes[0];       // 50000
    const int E2 = in_sizes[1];      // 2*E
    const int E = E2 / 2;
    const int NB = (N + BUCKET - 1) / BUCKET;   // 782

    const float* x    = (const float*)d_in[0];
    const void*  edge = d_in[1];
    const void*  batch= d_in[2];
    const float* W1l  = (const float*)d_in[3];
    const float* b1   = (const float*)d_in[4];
    const float* W1r  = (const float*)d_in[5];
    const float* W2l  = (const float*)d_in[6];
    const float* b2   = (const float*)d_in[7];
    const float* W2r  = (const float*)d_in[8];
    const float* W3l  = (const float*)d_in[9];
    const float* b3   = (const float*)d_in[10];
    const float* W3r  = (const float*)d_in[11];
    const float* Wfc1 = (const float*)d_in[12];
    const float* bfc1 = (const float*)d_in[13];
    const float* Wfc2 = (const float*)d_in[14];
    const float* bfc2 = (const float*)d_in[15];
    float* out = (float*)d_out;

    // Workspace layout (256 B aligned slices). Zero-init buffers first so
    // ONE memset covers bcnt + psum + gcnt.
    char* ws = (char*)d_ws;
    size_t o = 0;
    auto alloc = [&](size_t bytes) { char* p = ws + o; o += (bytes + 255) & ~(size_t)255; return p; };
    int*   bcnt    = (int*)alloc((size_t)NB * 4);
    float* psum    = (float*)alloc((size_t)NGRAPHS * HID * 4);
    int*   gcnt    = (int*)alloc((size_t)NGRAPHS * 4);
    size_t zero_bytes = o;
    int*   bbase   = (int*)alloc(((size_t)NB + 1) * 4);
    int*   bcursor = (int*)alloc((size_t)NB * 4);
    unsigned int* entries = (unsigned int*)alloc((size_t)E * 4);
    int*   rowptr  = (int*)alloc(((size_t)N + 1) * 4);
    int*   csr     = (int*)alloc((size_t)E * 4);
    float* h1      = (float*)alloc((size_t)N * HID * 4);   // reused as h3
    float* meanb   = (float*)alloc((size_t)N * HID * 4);
    float* h2      = (float*)alloc((size_t)N * HID * 4);
    int*   flags   = (int*)alloc(16);
    float* h3 = h1;

    hipMemsetAsync(ws, 0, zero_bytes, stream);

    // Index dtype detection
    detect_kernel<<<1, 64, 0, stream>>>(edge, batch, flags, E2, N, NGRAPHS);

    // Binned CSR build: count -> scan -> scatter -> per-bucket finalize
    const int nblk = (E + EPB - 1) / EPB;   // 196
    bin_count_kernel<<<nblk, 256, NB * 4, stream>>>(edge, flags, bcnt, E, NB);
    bin_scan_kernel<<<1, 1024, 0, stream>>>(bcnt, bbase, bcursor, NB);
    bin_scatter_kernel<<<nblk, 256, 2 * NB * 4, stream>>>(edge, flags, bcursor, entries, E, NB);
    csr_finalize_kernel<<<NB, 256, 0, stream>>>(entries, bbase, rowptr, csr, N, NB);

    // Layer 1 (fused gather + transform)
    layer1_kernel<<<(N + 255) / 256, 256, 0, stream>>>(rowptr, csr, x, W1l, b1, W1r, h1, N);

    const int nlWaves = NL_BLOCKS * 4;

    // Layer 2
    gather_mean_kernel<<<(N + 15) / 16, 256, 0, stream>>>(rowptr, csr, h1, meanb, N);
    node_layer_kernel<<<NL_BLOCKS, 256, 0, stream>>>(h1, meanb, W2l, b2, W2r, h2, N, nlWaves);

    // Layer 3
    gather_mean_kernel<<<(N + 15) / 16, 256, 0, stream>>>(rowptr, csr, h2, meanb, N);
    node_layer_kernel<<<NL_BLOCKS, 256, 0, stream>>>(h2, meanb, W3l, b3, W3r, h3, N, nlWaves);

    // Pool + FC head
    {
        int nodesPerWave = 64;
        int waves = (N + nodesPerWave - 1) / nodesPerWave;
        int threads = waves * 64;
        pool_kernel<<<(threads + 255) / 256, 256, 0, stream>>>(h3, batch, flags, psum, gcnt,
                                                               N, nodesPerWave);
    }
    fc_kernel<<<NGRAPHS, 64, 0, stream>>>(psum, gcnt, Wfc1, bfc1, Wfc2, bfc2, out);
}

// Round 8
// 288.016 us; speedup vs baseline: 3.4121x; 1.0398x over previous
//
#include <hip/hip_runtime.h>
#include <hip/hip_bf16.h>
#include <hip/hip_fp16.h>

#define HID 64
#define NGRAPHS 64
#define BUCKET 64        // nodes per bucket (dst >> 6)
#define EPB 4096         // edges per block in bin_count / bin_scatter
#define NL_BLOCKS 512    // node_layer grid (2048 waves)

// ---------------------------------------------------------------------------
// Detect whether edge_index / batch are int64 or int32 on device.
// ---------------------------------------------------------------------------
__global__ __launch_bounds__(64) void detect_kernel(const void* edge, const void* batch,
                                                    int* flags, int E2, int N, int G) {
    int lane = threadIdx.x;
    int half = E2 / 2;
    int stride = half / 64; if (stride < 1) stride = 1;
    int j = lane * stride; if (j >= half) j = half - 1;
    long long v = ((const long long*)edge)[j];
    bool ok = (v >= 0 && v < (long long)N);
    unsigned long long m = __ballot(ok);
    if (lane == 0) flags[0] = (m == ~0ULL) ? 1 : 0;
    int halfB = N / 2;
    int strideB = halfB / 64; if (strideB < 1) strideB = 1;
    int jb = lane * strideB; if (jb >= halfB) jb = halfB - 1;
    long long vb = ((const long long*)batch)[jb];
    bool okb = (vb >= 0 && vb < (long long)G);
    unsigned long long mb = __ballot(okb);
    if (lane == 0) flags[1] = (mb == ~0ULL) ? 1 : 0;
}

__device__ __forceinline__ int idx_at(const void* p, int i, bool is64) {
    return is64 ? (int)((const long long*)p)[i] : ((const int*)p)[i];
}

// ---------------------------------------------------------------------------
// Bucket histogram: LDS-local counts, one global add per (block, bucket).
// ---------------------------------------------------------------------------
__global__ __launch_bounds__(256) void bin_count_kernel(const void* edge, const int* __restrict__ flags,
                                                        int* __restrict__ bcnt, int E, int NB) {
    extern __shared__ int hist[];   // NB ints
    for (int i = threadIdx.x; i < NB; i += 256) hist[i] = 0;
    __syncthreads();
    bool is64 = flags[0] != 0;
    int start = blockIdx.x * EPB;
    int end = start + EPB; if (end > E) end = E;
    for (int e = start + threadIdx.x; e < end; e += 256) {
        int d = idx_at(edge, E + e, is64);
        atomicAdd(&hist[d >> 6], 1);
    }
    __syncthreads();
    for (int i = threadIdx.x; i < NB; i += 256) {
        int h = hist[i];
        if (h) atomicAdd(&bcnt[i], h);
    }
}

// ---------------------------------------------------------------------------
// Exclusive scan of bucket counts (NB <= 1024): bbase[NB+1], bcursor init.
// ---------------------------------------------------------------------------
__global__ __launch_bounds__(1024) void bin_scan_kernel(const int* __restrict__ bcnt,
                                                        int* __restrict__ bbase,
                                                        int* __restrict__ bcursor, int NB) {
    __shared__ int s[1024];
    int t = threadIdx.x;
    int v = (t < NB) ? bcnt[t] : 0;
    s[t] = v;
    __syncthreads();
    for (int off = 1; off < 1024; off <<= 1) {
        int tmp = (t >= off) ? s[t - off] : 0;
        __syncthreads();
        s[t] += tmp;
        __syncthreads();
    }
    if (t < NB) {
        int ex = s[t] - v;
        bbase[t] = ex;
        bcursor[t] = ex;
        if (t == NB - 1) bbase[NB] = s[t];
    }
}

// ---------------------------------------------------------------------------
// Bucket scatter: per-block histogram -> one range reservation per bucket ->
// contiguous packed-entry appends. entry = (src << 6) | (dst & 63).
// ---------------------------------------------------------------------------
__global__ __launch_bounds__(256) void bin_scatter_kernel(const void* edge, const int* __restrict__ flags,
                                                          int* __restrict__ bcursor,
                                                          unsigned int* __restrict__ entries,
                                                          int E, int NB) {
    extern __shared__ int lds[];    // hist[NB] + base[NB]
    int* hist = lds;
    int* base = lds + NB;
    for (int i = threadIdx.x; i < NB; i += 256) hist[i] = 0;
    __syncthreads();
    bool is64 = flags[0] != 0;
    int start = blockIdx.x * EPB;
    int end = start + EPB; if (end > E) end = E;
    for (int e = start + threadIdx.x; e < end; e += 256) {
        int d = idx_at(edge, E + e, is64);
        atomicAdd(&hist[d >> 6], 1);
    }
    __syncthreads();
    for (int i = threadIdx.x; i < NB; i += 256) {
        int h = hist[i];
        base[i] = h ? atomicAdd(&bcursor[i], h) : 0;
    }
    __syncthreads();
    for (int i = threadIdx.x; i < NB; i += 256) hist[i] = 0;  // reuse as local cursor
    __syncthreads();
    for (int e = start + threadIdx.x; e < end; e += 256) {
        int srcv = idx_at(edge, e, is64);
        int d = idx_at(edge, E + e, is64);
        int b = d >> 6;
        int lo = atomicAdd(&hist[b], 1);
        entries[base[b] + lo] = ((unsigned int)srcv << 6) | (unsigned int)(d & 63);
    }
}

// ---------------------------------------------------------------------------
// Per-bucket CSR finalize: histogram bucket's 64 dests, wave scan, write
// rowptr + csr within the bucket's contiguous window.
// ---------------------------------------------------------------------------
__global__ __launch_bounds__(256) void csr_finalize_kernel(const unsigned int* __restrict__ entries,
                                                           const int* __restrict__ bbase,
                                                           int* __restrict__ rowptr,
                                                           int* __restrict__ csr,
                                                           int N, int NB) {
    __shared__ int hist[BUCKET];
    __shared__ int lstart[BUCKET];
    __shared__ int lcur[BUCKET];
    int t = threadIdx.x;
    int b = blockIdx.x;
    if (t < BUCKET) { hist[t] = 0; lcur[t] = 0; }
    __syncthreads();
    int r0 = bbase[b], r1 = bbase[b + 1];
    for (int j = r0 + t; j < r1; j += 256) {
        atomicAdd(&hist[entries[j] & 63u], 1);
    }
    __syncthreads();
    if (t < BUCKET) {  // wave 0: 64-lane inclusive shuffle scan -> exclusive
        int v = hist[t];
        int s = v;
#pragma unroll
        for (int off = 1; off < 64; off <<= 1) {
            int u = __shfl_up(s, off);
            if (t >= off) s += u;
        }
        lstart[t] = s - v;
        int node = b * BUCKET + t;
        if (node < N) rowptr[node] = r0 + s - v;
        if (b == NB - 1 && t == 63) rowptr[N] = r1;
    }
    __syncthreads();
    for (int j = r0 + t; j < r1; j += 256) {
        unsigned int en = entries[j];
        int dl = (int)(en & 63u);
        int p = atomicAdd(&lcur[dl], 1);
        csr[r0 + lstart[dl] + p] = (int)(en >> 6);
    }
}

// ---------------------------------------------------------------------------
// Layer 1 fused: thread-per-node scalar neighbor mean into LDS, then
// 64-threads-per-node transform. Writes fp32 h1 AND fp16 copy for gather.
// ---------------------------------------------------------------------------
__global__ __launch_bounds__(256) void layer1_kernel(const int* __restrict__ rowptr,
                                                     const int* __restrict__ csr,
                                                     const float* __restrict__ x,
                                                     const float* __restrict__ W1l,
                                                     const float* __restrict__ b1,
                                                     const float* __restrict__ W1r,
                                                     float* __restrict__ h1,
                                                     __half* __restrict__ h1h, int N) {
    __shared__ float smean[256];
    __shared__ float sx[256];
    int t = threadIdx.x;
    int i0 = blockIdx.x * 256;
    int i = i0 + t;
    if (i < N) {
        int r0 = rowptr[i], r1 = rowptr[i + 1];
        float s = 0.0f;
        for (int j = r0; j < r1; ++j) s += x[csr[j]];
        smean[t] = (r1 > r0) ? s / (float)(r1 - r0) : 0.0f;
        sx[t] = x[i];
    }
    __syncthreads();
    int f = t & 63;
    int sub = t >> 6;   // 0..3
    float wlf = W1l[f], bf = b1[f], wrf = W1r[f];
    for (int it = 0; it < 64; ++it) {
        int nl = it * 4 + sub;
        int node = i0 + nl;
        if (node < N) {
            float mv = smean[nl], xv = sx[nl];
            float v = fmaf(mv, wlf, fmaf(xv, wrf, bf));
            v = v > 0.0f ? v : 0.0f;
            float hv = v + xv;
            h1[(size_t)node * HID + f] = hv;
            h1h[(size_t)node * HID + f] = __float2half(hv);
        }
    }
}

// ---------------------------------------------------------------------------
// Layers 2/3 aggregation via gather on fp16 rows: 8 lanes per node, each lane
// one uint4 (16 B = 8 halfs). 4x unroll, dual accumulators. Mean written fp32.
// ---------------------------------------------------------------------------
__global__ __launch_bounds__(256) void gather_mean_kernel(const int* __restrict__ rowptr,
                                                          const int* __restrict__ csr,
                                                          const __half* __restrict__ h,
                                                          float* __restrict__ mean, int N) {
    int grp = threadIdx.x >> 3;      // 32 groups per block
    int l = threadIdx.x & 7;         // lane within group -> 8 features
    int i = blockIdx.x * 32 + grp;
    if (i >= N) return;
    int r0 = rowptr[i], r1 = rowptr[i + 1];
    float a0[8], a1[8];
#pragma unroll
    for (int k = 0; k < 8; ++k) { a0[k] = 0.0f; a1[k] = 0.0f; }
    int j = r0;
    for (; j + 4 <= r1; j += 4) {
        int s0 = csr[j], s1 = csr[j + 1], s2 = csr[j + 2], s3 = csr[j + 3];
        uint4 u0 = *(const uint4*)(h + (size_t)s0 * HID + l * 8);
        uint4 u1 = *(const uint4*)(h + (size_t)s1 * HID + l * 8);
        uint4 u2 = *(const uint4*)(h + (size_t)s2 * HID + l * 8);
        uint4 u3 = *(const uint4*)(h + (size_t)s3 * HID + l * 8);
        const __half2* p0 = (const __half2*)&u0;
        const __half2* p1 = (const __half2*)&u1;
        const __half2* p2 = (const __half2*)&u2;
        const __half2* p3 = (const __half2*)&u3;
#pragma unroll
        for (int q = 0; q < 4; ++q) {
            float2 f0 = __half22float2(p0[q]);
            float2 f1 = __half22float2(p1[q]);
            float2 f2 = __half22float2(p2[q]);
            float2 f3 = __half22float2(p3[q]);
            a0[2 * q]     += f0.x + f1.x;
            a0[2 * q + 1] += f0.y + f1.y;
            a1[2 * q]     += f2.x + f3.x;
            a1[2 * q + 1] += f2.y + f3.y;
        }
    }
    for (; j < r1; ++j) {
        int s = csr[j];
        uint4 u0 = *(const uint4*)(h + (size_t)s * HID + l * 8);
        const __half2* p0 = (const __half2*)&u0;
#pragma unroll
        for (int q = 0; q < 4; ++q) {
            float2 f0 = __half22float2(p0[q]);
            a0[2 * q] += f0.x;
            a0[2 * q + 1] += f0.y;
        }
    }
    float inv = (r1 > r0) ? 1.0f / (float)(r1 - r0) : 0.0f;
    float4 o0, o1;
    o0.x = (a0[0] + a1[0]) * inv; o0.y = (a0[1] + a1[1]) * inv;
    o0.z = (a0[2] + a1[2]) * inv; o0.w = (a0[3] + a1[3]) * inv;
    o1.x = (a0[4] + a1[4]) * inv; o1.y = (a0[5] + a1[5]) * inv;
    o1.z = (a0[6] + a1[6]) * inv; o1.w = (a0[7] + a1[7]) * inv;
    float* mrow = mean + (size_t)i * HID + l * 8;
    *(float4*)(mrow) = o0;
    *(float4*)(mrow + 4) = o1;
}

// ---------------------------------------------------------------------------
// Layers 2/3 node transform — register-weight / scalar-row version.
// Writes fp32 hout AND fp16 copy (for next layer's gather).
// ---------------------------------------------------------------------------
__global__ __launch_bounds__(256) void node_layer_kernel(const float* __restrict__ hprev,
                                                         const float* __restrict__ mean,
                                                         const float* __restrict__ Wl,
                                                         const float* __restrict__ bvec,
                                                         const float* __restrict__ Wr,
                                                         float* __restrict__ hout,
                                                         __half* __restrict__ houth,
                                                         int N, int nwaves) {
    int f = threadIdx.x & 63;
    int wid = (blockIdx.x * blockDim.x + threadIdx.x) >> 6;
    float wl[HID], wr[HID];
#pragma unroll
    for (int k = 0; k < HID; ++k) {
        wl[k] = Wl[k * HID + f];
        wr[k] = Wr[k * HID + f];
    }
    float bf = bvec[f];
    for (int i = wid; i < N; i += nwaves) {
        int iu = __builtin_amdgcn_readfirstlane(i);
        const float* mrow = mean + (size_t)iu * HID;
        const float* hrow = hprev + (size_t)iu * HID;
        float hpv = hrow[f];
        float acc = bf;
#pragma unroll
        for (int k = 0; k < HID; ++k) {
            acc = fmaf(mrow[k], wl[k], acc);
            acc = fmaf(hrow[k], wr[k], acc);
        }
        float r = acc > 0.0f ? acc : 0.0f;
        float hv = r + hpv;
        hout[(size_t)iu * HID + f] = hv;
        houth[(size_t)iu * HID + f] = __float2half(hv);
    }
}

// ---------------------------------------------------------------------------
// Global mean pool: batch is sorted -> run-length accumulate per wave.
// ---------------------------------------------------------------------------
__global__ __launch_bounds__(256) void pool_kernel(const float* __restrict__ h,
                                                   const void* batch,
                                                   const int* __restrict__ flags,
                                                   float* __restrict__ psum,
                                                   int* __restrict__ gcnt,
                                                   int N, int nodesPerWave) {
    int wave = (blockIdx.x * blockDim.x + threadIdx.x) >> 6;
    int f = threadIdx.x & 63;
    int start = wave * nodesPerWave;
    if (start >= N) return;
    bool is64 = flags[1] != 0;
    int end = start + nodesPerWave;
    if (end > N) end = N;
    int g = idx_at(batch, start, is64);
    float acc = 0.0f;
    int c = 0;
    for (int i = start; i < end; ++i) {
        int gi = idx_at(batch, i, is64);
        if (gi != g) {
            atomicAdd(&psum[g * HID + f], acc);
            if (f == 0) atomicAdd(&gcnt[g], c);
            acc = 0.0f; c = 0; g = gi;
        }
        acc += h[(size_t)i * HID + f];
        c++;
    }
    atomicAdd(&psum[g * HID + f], acc);
    if (f == 0) atomicAdd(&gcnt[g], c);
}

// ---------------------------------------------------------------------------
// FC head: one block (64 threads) per graph.
// ---------------------------------------------------------------------------
__global__ __launch_bounds__(64) void fc_kernel(const float* __restrict__ psum,
                                                const int* __restrict__ gcnt,
                                                const float* __restrict__ Wfc1,
                                                const float* __restrict__ bfc1,
                                                const float* __restrict__ Wfc2,
                                                const float* __restrict__ bfc2,
                                                float* __restrict__ out) {
    int g = blockIdx.x;
    int t = threadIdx.x;
    __shared__ float mean[HID];
    float c = fmaxf((float)gcnt[g], 1.0f);
    mean[t] = psum[g * HID + t] / c;
    __syncthreads();
    float v = 0.0f;
    if (t < 32) {
        float acc = bfc1[t];
#pragma unroll
        for (int k = 0; k < HID; ++k) acc += mean[k] * Wfc1[k * 32 + t];
        float hcc = acc > 0.0f ? acc : 0.0f;
        v = hcc * Wfc2[t];
    }
#pragma unroll
    for (int off = 32; off >= 1; off >>= 1) v += __shfl_down(v, off);
    if (t == 0) out[g] = v + bfc2[0];
}

extern "C" void kernel_launch(void* const* d_in, const int* in_sizes, int n_in,
                              void* d_out, int out_size, void* d_ws, size_t ws_size,
                              hipStream_t stream) {
    const int N = in_sizes[0];       // 50000
    const int E2 = in_sizes[1];      // 2*E
    const int E = E2 / 2;
    const int NB = (N + BUCKET - 1) / BUCKET;   // 782

    const float* x    = (const float*)d_in[0];
    const void*  edge = d_in[1];
    const void*  batch= d_in[2];
    const float* W1l  = (const float*)d_in[3];
    const float* b1   = (const float*)d_in[4];
    const float* W1r  = (const float*)d_in[5];
    const float* W2l  = (const float*)d_in[6];
    const float* b2   = (const float*)d_in[7];
    const float* W2r  = (const float*)d_in[8];
    const float* W3l  = (const float*)d_in[9];
    const float* b3   = (const float*)d_in[10];
    const float* W3r  = (const float*)d_in[11];
    const float* Wfc1 = (const float*)d_in[12];
    const float* bfc1 = (const float*)d_in[13];
    const float* Wfc2 = (const float*)d_in[14];
    const float* bfc2 = (const float*)d_in[15];
    float* out = (float*)d_out;

    // Workspace layout (256 B aligned slices). Zero-init buffers first so
    // ONE memset covers bcnt + psum + gcnt.
    char* ws = (char*)d_ws;
    size_t o = 0;
    auto alloc = [&](size_t bytes) { char* p = ws + o; o += (bytes + 255) & ~(size_t)255; return p; };
    int*   bcnt    = (int*)alloc((size_t)NB * 4);
    float* psum    = (float*)alloc((size_t)NGRAPHS * HID * 4);
    int*   gcnt    = (int*)alloc((size_t)NGRAPHS * 4);
    size_t zero_bytes = o;
    int*   bbase   = (int*)alloc(((size_t)NB + 1) * 4);
    int*   bcursor = (int*)alloc((size_t)NB * 4);
    unsigned int* entries = (unsigned int*)alloc((size_t)E * 4);
    int*   rowptr  = (int*)alloc(((size_t)N + 1) * 4);
    int*   csr     = (int*)alloc((size_t)E * 4);
    float* h1      = (float*)alloc((size_t)N * HID * 4);   // reused as h3
    float* meanb   = (float*)alloc((size_t)N * HID * 4);
    float* h2      = (float*)alloc((size_t)N * HID * 4);
    __half* h1h    = (__half*)alloc((size_t)N * HID * 2);  // fp16 copy for gather
    __half* h2h    = (__half*)alloc((size_t)N * HID * 2);
    int*   flags   = (int*)alloc(16);
    float* h3 = h1;
    __half* h3h = h1h;   // dead sink for layer-3 fp16 write (h1h no longer read)

    hipMemsetAsync(ws, 0, zero_bytes, stream);

    // Index dtype detection
    detect_kernel<<<1, 64, 0, stream>>>(edge, batch, flags, E2, N, NGRAPHS);

    // Binned CSR build: count -> scan -> scatter -> per-bucket finalize
    const int nblk = (E + EPB - 1) / EPB;   // 196
    bin_count_kernel<<<nblk, 256, NB * 4, stream>>>(edge, flags, bcnt, E, NB);
    bin_scan_kernel<<<1, 1024, 0, stream>>>(bcnt, bbase, bcursor, NB);
    bin_scatter_kernel<<<nblk, 256, 2 * NB * 4, stream>>>(edge, flags, bcursor, entries, E, NB);
    csr_finalize_kernel<<<NB, 256, 0, stream>>>(entries, bbase, rowptr, csr, N, NB);

    // Layer 1 (fused gather + transform; writes fp32 + fp16 h1)
    layer1_kernel<<<(N + 255) / 256, 256, 0, stream>>>(rowptr, csr, x, W1l, b1, W1r, h1, h1h, N);

    const int nlWaves = NL_BLOCKS * 4;

    // Layer 2
    gather_mean_kernel<<<(N + 31) / 32, 256, 0, stream>>>(rowptr, csr, h1h, meanb, N);
    node_layer_kernel<<<NL_BLOCKS, 256, 0, stream>>>(h1, meanb, W2l, b2, W2r, h2, h2h, N, nlWaves);

    // Layer 3
    gather_mean_kernel<<<(N + 31) / 32, 256, 0, stream>>>(rowptr, csr, h2h, meanb, N);
    node_layer_kernel<<<NL_BLOCKS, 256, 0, stream>>>(h2, meanb, W3l, b3, W3r, h3, h3h, N, nlWaves);

    // Pool + FC head
    {
        int nodesPerWave = 64;
        int waves = (N + nodesPerWave - 1) / nodesPerWave;
        int threads = waves * 64;
        pool_kernel<<<(threads + 255) / 256, 256, 0, stream>>>(h3, batch, flags, psum, gcnt,
                                                               N, nodesPerWave);
    }
    fc_kernel<<<NGRAPHS, 64, 0, stream>>>(psum, gcnt, Wfc1, bfc1, Wfc2, bfc2, out);
}